// Round 7
// baseline (765.175 us; speedup 1.0000x reference)
//
#include <hip/hip_runtime.h>
#include <cstdint>
#include <cmath>

// Round-7: flash_attn v2 -- V pre-transposed in global (VtG), PV B-fragments
// loaded directly from global, NO barriers in the k-loop (Pl is wave-private,
// ordered by __threadfence_block). Pl stride 40 (aligned, fewer conflicts).
// Rest of pipeline unchanged from round 6.
//
// B=2, T=2048, D=2048, H=16, G=4, DK=128. f32 in / f32 out.
// ws (54.6 MB):
//   xb/y   [4096x2048 bf16]          (xb dead after gemm1 -> y aliases)
//   WT     [3072x2048 bf16]          (after gemm1: WoT = first 4.19M elems,
//                                     VtG = last 2.10M elems -- exact fit)
//   qkv    [4096x3072 bf16]

#define GLOBAL_AS __attribute__((address_space(1)))
#define LDS_AS __attribute__((address_space(3)))

typedef __bf16 bf16x8 __attribute__((ext_vector_type(8)));
typedef __bf16 bf16x4 __attribute__((ext_vector_type(4)));
typedef float f32x4 __attribute__((ext_vector_type(4)));

constexpr int Tn = 2048;

__device__ __forceinline__ f32x4 mfma_bf16(bf16x8 a, bf16x8 b, f32x4 c) {
  return __builtin_amdgcn_mfma_f32_16x16x32_bf16(a, b, c, 0, 0, 0);
}

// ---------------------------------------------------------------- convert f32 -> bf16
__global__ __launch_bounds__(256) void convert_f32_bf16(const float* __restrict__ src,
                                                        __bf16* __restrict__ dst,
                                                        size_t n4) {
  const size_t i = (size_t)blockIdx.x * 256 + threadIdx.x;
  if (i >= n4) return;
  const f32x4 v = ((const f32x4*)src)[i];
  bf16x4 o;
#pragma unroll
  for (int k = 0; k < 4; ++k) o[k] = (__bf16)v[k];
  ((bf16x4*)dst)[i] = o;
}

// ---------------------------------------------------------------- transpose+convert
// src f32: K rows x N cols -> dst bf16: N rows x K cols.
__global__ __launch_bounds__(256) void transpose_f32_bf16(const float* __restrict__ src,
                                                          __bf16* __restrict__ dst,
                                                          int K, int N) {
  __shared__ __bf16 tile[32][33];
  const int n0 = blockIdx.x * 32, k0 = blockIdx.y * 32;
  const int tx = threadIdx.x, ty = threadIdx.y;
#pragma unroll
  for (int i = 0; i < 32; i += 8)
    tile[ty + i][tx] = (__bf16)src[(size_t)(k0 + ty + i) * N + n0 + tx];
  __syncthreads();
#pragma unroll
  for (int i = 0; i < 32; i += 8)
    dst[(size_t)(n0 + ty + i) * K + k0 + tx] = tile[tx][ty + i];
}

// ---------------------------------------------------------------- transpose V (bf16)
// qkv V-slice [key][dim] (stride 3072) -> VtG[(b*4+g)][dim][key] (stride Tn).
// grid: (Tn/32, 128/32, 8); block (32,8).
__global__ __launch_bounds__(256) void transpose_v(const __bf16* __restrict__ qkv,
                                                   __bf16* __restrict__ vtg) {
  __shared__ __bf16 tile[32][33];
  const int bg = blockIdx.z;           // b*4+g
  const int b = bg >> 2, g = bg & 3;
  const int key0 = blockIdx.x * 32, d0 = blockIdx.y * 32;
  const int tx = threadIdx.x, ty = threadIdx.y;
  const __bf16* src = qkv + (size_t)b * Tn * 3072 + 2560 + g * 128;
  __bf16* dst = vtg + (size_t)bg * 128 * Tn;
#pragma unroll
  for (int i = 0; i < 32; i += 8)
    tile[ty + i][tx] = src[(size_t)(key0 + ty + i) * 3072 + d0 + tx];
  __syncthreads();
#pragma unroll
  for (int i = 0; i < 32; i += 8)
    dst[(size_t)(d0 + ty + i) * Tn + key0 + tx] = tile[tx][ty + i];
}

// ---------------------------------------------------------------- GEMM (B^T)
// C[M][N] = A[M][K] @ BT[N][K]^T. 128x128 tile, BK=32, 4 waves (2x2 of 64x64),
// global_load_lds width=16 staging, 16x16x32 bf16 MFMA. outf32: C is float*.
__global__ __launch_bounds__(256) void gemm_bt(const __bf16* __restrict__ A,
                                               const __bf16* __restrict__ BT,
                                               void* __restrict__ C,
                                               int K, int ldc, int outf32) {
  __shared__ __attribute__((aligned(16))) __bf16 As[128 * 32];
  __shared__ __attribute__((aligned(16))) __bf16 Bs[128 * 32];
  const int tid = threadIdx.x;
  const int wave = tid >> 6, lane = tid & 63;
  const int lr = lane & 15, lq = lane >> 4;
  const int wm = wave >> 1, wn = wave & 1;
  const int m0 = blockIdx.y * 128, n0 = blockIdx.x * 128;

  f32x4 acc[4][4] = {};

  const int srow = tid >> 2;
  const int scol = (tid & 3) * 8;
  const __bf16* ga = A + (size_t)(m0 + srow) * K + scol;
  const __bf16* gb = BT + (size_t)(n0 + srow) * K + scol;

  for (int kt = 0; kt < K; kt += 32) {
    __syncthreads();
#pragma unroll
    for (int it = 0; it < 2; ++it) {
      __builtin_amdgcn_global_load_lds((GLOBAL_AS void*)(ga + (size_t)it * 64 * K + kt),
                                       (LDS_AS void*)(As + it * 2048 + wave * 512), 16, 0, 0);
      __builtin_amdgcn_global_load_lds((GLOBAL_AS void*)(gb + (size_t)it * 64 * K + kt),
                                       (LDS_AS void*)(Bs + it * 2048 + wave * 512), 16, 0, 0);
    }
    __syncthreads();

    bf16x8 af[4], bfv[4];
#pragma unroll
    for (int i = 0; i < 4; ++i)
      af[i] = *(const bf16x8*)(As + (wm * 64 + i * 16 + lr) * 32 + lq * 8);
#pragma unroll
    for (int j = 0; j < 4; ++j)
      bfv[j] = *(const bf16x8*)(Bs + (wn * 64 + j * 16 + lr) * 32 + lq * 8);
#pragma unroll
    for (int i = 0; i < 4; ++i)
#pragma unroll
      for (int j = 0; j < 4; ++j)
        acc[i][j] = mfma_bf16(af[i], bfv[j], acc[i][j]);
  }

#pragma unroll
  for (int i = 0; i < 4; ++i) {
    const int row = m0 + wm * 64 + i * 16 + lq * 4;
#pragma unroll
    for (int j = 0; j < 4; ++j) {
      const int col = n0 + wn * 64 + j * 16 + lr;
#pragma unroll
      for (int r = 0; r < 4; ++r) {
        if (outf32)
          ((float*)C)[(size_t)(row + r) * ldc + col] = acc[i][j][r];
        else
          ((__bf16*)C)[(size_t)(row + r) * ldc + col] = (__bf16)acc[i][j][r];
      }
    }
  }
}

// ---------------------------------------------------------------- RoPE
// Q cols h*128+d, K cols 2048+g*128+d; pair (d, d+64), d<64; pos = t.
__global__ __launch_bounds__(256) void rope_kernel(__bf16* __restrict__ qkv) {
  const int row = blockIdx.x;
  const int t = row & (Tn - 1);
  for (int p = threadIdx.x; p < 1280; p += 256) {
    const int d = p & 63;
    const int hh = p >> 6;
    const int col = (hh < 16) ? (hh * 128 + d) : (2048 + (hh - 16) * 128 + d);
    const float inv = exp2f((float)d * (-13.287712379549449f / 64.f));
    const float ang = (float)t * inv;
    float sn, cs;
    __sincosf(ang, &sn, &cs);
    __bf16* ptr = qkv + (size_t)row * 3072 + col;
    const float x1 = (float)ptr[0];
    const float x2 = (float)ptr[64];
    ptr[0] = (__bf16)(x1 * cs - x2 * sn);
    ptr[64] = (__bf16)(x2 * cs + x1 * sn);
  }
}

// ---------------------------------------------------------------- flash attention v2
// grid: (T/64, B*H). 4 waves/block, wave w owns Q rows q0+w*16..+16.
// K and V^T fragments straight from global; Pl (wave-private) is the only LDS.
// NO barriers in the k-loop.
__global__ __launch_bounds__(256) void flash_attn(const __bf16* __restrict__ qkv,
                                                  const __bf16* __restrict__ vtg,
                                                  __bf16* __restrict__ y) {
  const int b = blockIdx.y >> 4, h = blockIdx.y & 15;
  const int g = h >> 2;  // rf = 4
  const int q0 = blockIdx.x * 64;
  const int tid = threadIdx.x;
  const int wave = tid >> 6, lane = tid & 63;
  const int lr = lane & 15, lq = lane >> 4;

  const __bf16* Qb = qkv + (size_t)b * Tn * 3072 + h * 128;
  const __bf16* Kb = qkv + (size_t)b * Tn * 3072 + 2048 + g * 128;
  const __bf16* Vt = vtg + (size_t)(b * 4 + g) * 128 * Tn;  // [dim][key]

  __shared__ __attribute__((aligned(16))) __bf16 Pl[4][16 * 40];  // stride 40: aligned b128 reads

  // Q tile, A-operand layout: frag f = dims f*32 + lq*8 .. +8, row lr
  const int qrow = q0 + wave * 16 + lr;
  bf16x8 qf[4];
#pragma unroll
  for (int f = 0; f < 4; ++f)
    qf[f] = *(const bf16x8*)(Qb + (size_t)qrow * 3072 + f * 32 + lq * 8);

  f32x4 o[8] = {};
  float m_i[4], l_i[4];
#pragma unroll
  for (int r = 0; r < 4; ++r) { m_i[r] = -1e30f; l_i[r] = 0.f; }
  const float scale = 0.08838834764831845f;  // 1/sqrt(128)

  for (int kt = 0; kt < q0 + 64; kt += 32) {
    // S = Q K^T : two 16-key tiles (keys kt..+15, kt+16..+31)
    f32x4 s0 = {}, s1 = {};
#pragma unroll
    for (int f = 0; f < 4; ++f) {
      bf16x8 kf = *(const bf16x8*)(Kb + (size_t)(kt + lr) * 3072 + f * 32 + lq * 8);
      s0 = mfma_bf16(qf[f], kf, s0);
    }
#pragma unroll
    for (int f = 0; f < 4; ++f) {
      bf16x8 kf = *(const bf16x8*)(Kb + (size_t)(kt + 16 + lr) * 3072 + f * 32 + lq * 8);
      s1 = mfma_bf16(qf[f], kf, s1);
    }

    // prefetch V^T B-fragments (dim slice n*16+lr, keys kt+lq*8..+8)
    bf16x8 vv[8];
#pragma unroll
    for (int n = 0; n < 8; ++n)
      vv[n] = *(const bf16x8*)(Vt + (size_t)(n * 16 + lr) * Tn + kt + lq * 8);

    // online softmax (row lq*4+r, key cols lr / lr+16)
#pragma unroll
    for (int r = 0; r < 4; ++r) {
      const int q = q0 + wave * 16 + lq * 4 + r;
      const bool v0ok = (kt + lr) <= q;
      const bool v1ok = (kt + 16 + lr) <= q;
      float a0 = v0ok ? s0[r] * scale : -1e30f;
      float a1 = v1ok ? s1[r] * scale : -1e30f;
      float mx = fmaxf(a0, a1);
      mx = fmaxf(mx, __shfl_xor(mx, 1));
      mx = fmaxf(mx, __shfl_xor(mx, 2));
      mx = fmaxf(mx, __shfl_xor(mx, 4));
      mx = fmaxf(mx, __shfl_xor(mx, 8));
      const float mnew = fmaxf(m_i[r], mx);
      const float p0 = v0ok ? __expf(a0 - mnew) : 0.f;
      const float p1 = v1ok ? __expf(a1 - mnew) : 0.f;
      float rs = p0 + p1;
      rs += __shfl_xor(rs, 1);
      rs += __shfl_xor(rs, 2);
      rs += __shfl_xor(rs, 4);
      rs += __shfl_xor(rs, 8);
      const float alpha = __expf(m_i[r] - mnew);
      m_i[r] = mnew;
      l_i[r] = l_i[r] * alpha + rs;
#pragma unroll
      for (int n = 0; n < 8; ++n) o[n][r] *= alpha;
      Pl[wave][(lq * 4 + r) * 40 + lr] = (__bf16)p0;
      Pl[wave][(lq * 4 + r) * 40 + 16 + lr] = (__bf16)p1;
    }

    // Pl is wave-private: lgkmcnt drain + compiler fence orders write->read.
    __threadfence_block();

    // P (C-layout) -> A-layout frag; PV accumulate
    bf16x8 pa = *(const bf16x8*)(&Pl[wave][lr * 40 + lq * 8]);
#pragma unroll
    for (int n = 0; n < 8; ++n)
      o[n] = mfma_bf16(pa, vv[n], o[n]);
  }

#pragma unroll
  for (int r = 0; r < 4; ++r) {
    const int q = q0 + wave * 16 + lq * 4 + r;
    const float inv = 1.0f / l_i[r];
#pragma unroll
    for (int n = 0; n < 8; ++n)
      y[(size_t)(b * Tn + q) * 2048 + h * 128 + n * 16 + lr] = (__bf16)(o[n][r] * inv);
  }
}

// ---------------------------------------------------------------- launch
extern "C" void kernel_launch(void* const* d_in, const int* in_sizes, int n_in,
                              void* d_out, int out_size, void* d_ws, size_t ws_size,
                              hipStream_t stream) {
  (void)in_sizes; (void)n_in; (void)out_size; (void)ws_size;
  const float* x  = (const float*)d_in[0];
  const float* Wq = (const float*)d_in[1];
  const float* Wk = (const float*)d_in[2];
  const float* Wv = (const float*)d_in[3];
  const float* Wo = (const float*)d_in[4];
  float* out = (float*)d_out;

  __bf16* xb  = (__bf16*)d_ws;                  // [4096][2048]; y aliases after gemm1
  __bf16* y   = xb;
  __bf16* WT  = xb + (size_t)4096 * 2048;       // [3072][2048]
  __bf16* WoT = WT;                             // [2048][2048] aliases WT after gemm1
  __bf16* VtG = WT + (size_t)2048 * 2048;       // [8][128][2048] fills rest of WT region
  __bf16* qkv = WT + (size_t)3072 * 2048;       // [4096][3072]

  convert_f32_bf16<<<(4096 * 2048 / 4 + 255) / 256, 256, 0, stream>>>(x, xb, 4096 * 2048 / 4);
  dim3 tb(32, 8);
  transpose_f32_bf16<<<dim3(64, 64), tb, 0, stream>>>(Wq, WT, 2048, 2048);
  transpose_f32_bf16<<<dim3(16, 64), tb, 0, stream>>>(Wk, WT + (size_t)2048 * 2048, 2048, 512);
  transpose_f32_bf16<<<dim3(16, 64), tb, 0, stream>>>(Wv, WT + (size_t)2560 * 2048, 2048, 512);

  gemm_bt<<<dim3(3072 / 128, 4096 / 128), 256, 0, stream>>>(xb, WT, qkv, 2048, 3072, 0);
  rope_kernel<<<4096, 256, 0, stream>>>(qkv);

  // WT region is dead now: write WoT + VtG into it.
  transpose_v<<<dim3(Tn / 32, 4, 8), tb, 0, stream>>>(qkv, VtG);
  transpose_f32_bf16<<<dim3(64, 64), tb, 0, stream>>>(Wo, WoT, 2048, 2048);

  flash_attn<<<dim3(Tn / 64, 2 * 16), 256, 0, stream>>>(qkv, VtG, y);
  gemm_bt<<<dim3(2048 / 128, 4096 / 128), 256, 0, stream>>>(y, WoT, out, 2048, 2048, 1);
}

// Round 8
// 505.924 us; speedup vs baseline: 1.5124x; 1.5124x over previous
//
#include <hip/hip_runtime.h>
#include <cstdint>
#include <cmath>

// Round-8: flash_attn v3 -- K-tile AND V^T-tile cooperatively staged in LDS
// with b128-only access at padded strides (136 / 40) => near bank floor.
// VtG (global V^T) kept so V staging is vector loads (no scalar transpose).
// Longest causal blocks dispatched first (reversed q-block order).
// Pipeline otherwise as round 7.
//
// B=2, T=2048, D=2048, H=16, G=4, DK=128. f32 in / f32 out.
// ws (54.6 MB): xb/y [4096x2048] | WT(->WoT+VtG) [3072x2048] | qkv [4096x3072]

#define GLOBAL_AS __attribute__((address_space(1)))
#define LDS_AS __attribute__((address_space(3)))

typedef __bf16 bf16x8 __attribute__((ext_vector_type(8)));
typedef __bf16 bf16x4 __attribute__((ext_vector_type(4)));
typedef float f32x4 __attribute__((ext_vector_type(4)));

constexpr int Tn = 2048;

__device__ __forceinline__ f32x4 mfma_bf16(bf16x8 a, bf16x8 b, f32x4 c) {
  return __builtin_amdgcn_mfma_f32_16x16x32_bf16(a, b, c, 0, 0, 0);
}

// ---------------------------------------------------------------- convert f32 -> bf16
__global__ __launch_bounds__(256) void convert_f32_bf16(const float* __restrict__ src,
                                                        __bf16* __restrict__ dst,
                                                        size_t n4) {
  const size_t i = (size_t)blockIdx.x * 256 + threadIdx.x;
  if (i >= n4) return;
  const f32x4 v = ((const f32x4*)src)[i];
  bf16x4 o;
#pragma unroll
  for (int k = 0; k < 4; ++k) o[k] = (__bf16)v[k];
  ((bf16x4*)dst)[i] = o;
}

// ---------------------------------------------------------------- transpose+convert
__global__ __launch_bounds__(256) void transpose_f32_bf16(const float* __restrict__ src,
                                                          __bf16* __restrict__ dst,
                                                          int K, int N) {
  __shared__ __bf16 tile[32][33];
  const int n0 = blockIdx.x * 32, k0 = blockIdx.y * 32;
  const int tx = threadIdx.x, ty = threadIdx.y;
#pragma unroll
  for (int i = 0; i < 32; i += 8)
    tile[ty + i][tx] = (__bf16)src[(size_t)(k0 + ty + i) * N + n0 + tx];
  __syncthreads();
#pragma unroll
  for (int i = 0; i < 32; i += 8)
    dst[(size_t)(n0 + ty + i) * K + k0 + tx] = tile[tx][ty + i];
}

// ---------------------------------------------------------------- transpose V (bf16)
// qkv V-slice [key][dim] -> VtG[(b*4+g)][dim][key] (stride Tn).
__global__ __launch_bounds__(256) void transpose_v(const __bf16* __restrict__ qkv,
                                                   __bf16* __restrict__ vtg) {
  __shared__ __bf16 tile[32][33];
  const int bg = blockIdx.z;
  const int b = bg >> 2, g = bg & 3;
  const int key0 = blockIdx.x * 32, d0 = blockIdx.y * 32;
  const int tx = threadIdx.x, ty = threadIdx.y;
  const __bf16* src = qkv + (size_t)b * Tn * 3072 + 2560 + g * 128;
  __bf16* dst = vtg + (size_t)bg * 128 * Tn;
#pragma unroll
  for (int i = 0; i < 32; i += 8)
    tile[ty + i][tx] = src[(size_t)(key0 + ty + i) * 3072 + d0 + tx];
  __syncthreads();
#pragma unroll
  for (int i = 0; i < 32; i += 8)
    dst[(size_t)(d0 + ty + i) * Tn + key0 + tx] = tile[tx][ty + i];
}

// ---------------------------------------------------------------- GEMM (B^T)
__global__ __launch_bounds__(256) void gemm_bt(const __bf16* __restrict__ A,
                                               const __bf16* __restrict__ BT,
                                               void* __restrict__ C,
                                               int K, int ldc, int outf32) {
  __shared__ __attribute__((aligned(16))) __bf16 As[128 * 32];
  __shared__ __attribute__((aligned(16))) __bf16 Bs[128 * 32];
  const int tid = threadIdx.x;
  const int wave = tid >> 6, lane = tid & 63;
  const int lr = lane & 15, lq = lane >> 4;
  const int wm = wave >> 1, wn = wave & 1;
  const int m0 = blockIdx.y * 128, n0 = blockIdx.x * 128;

  f32x4 acc[4][4] = {};

  const int srow = tid >> 2;
  const int scol = (tid & 3) * 8;
  const __bf16* ga = A + (size_t)(m0 + srow) * K + scol;
  const __bf16* gb = BT + (size_t)(n0 + srow) * K + scol;

  for (int kt = 0; kt < K; kt += 32) {
    __syncthreads();
#pragma unroll
    for (int it = 0; it < 2; ++it) {
      __builtin_amdgcn_global_load_lds((GLOBAL_AS void*)(ga + (size_t)it * 64 * K + kt),
                                       (LDS_AS void*)(As + it * 2048 + wave * 512), 16, 0, 0);
      __builtin_amdgcn_global_load_lds((GLOBAL_AS void*)(gb + (size_t)it * 64 * K + kt),
                                       (LDS_AS void*)(Bs + it * 2048 + wave * 512), 16, 0, 0);
    }
    __syncthreads();

    bf16x8 af[4], bfv[4];
#pragma unroll
    for (int i = 0; i < 4; ++i)
      af[i] = *(const bf16x8*)(As + (wm * 64 + i * 16 + lr) * 32 + lq * 8);
#pragma unroll
    for (int j = 0; j < 4; ++j)
      bfv[j] = *(const bf16x8*)(Bs + (wn * 64 + j * 16 + lr) * 32 + lq * 8);
#pragma unroll
    for (int i = 0; i < 4; ++i)
#pragma unroll
      for (int j = 0; j < 4; ++j)
        acc[i][j] = mfma_bf16(af[i], bfv[j], acc[i][j]);
  }

#pragma unroll
  for (int i = 0; i < 4; ++i) {
    const int row = m0 + wm * 64 + i * 16 + lq * 4;
#pragma unroll
    for (int j = 0; j < 4; ++j) {
      const int col = n0 + wn * 64 + j * 16 + lr;
#pragma unroll
      for (int r = 0; r < 4; ++r) {
        if (outf32)
          ((float*)C)[(size_t)(row + r) * ldc + col] = acc[i][j][r];
        else
          ((__bf16*)C)[(size_t)(row + r) * ldc + col] = (__bf16)acc[i][j][r];
      }
    }
  }
}

// ---------------------------------------------------------------- RoPE
__global__ __launch_bounds__(256) void rope_kernel(__bf16* __restrict__ qkv) {
  const int row = blockIdx.x;
  const int t = row & (Tn - 1);
  for (int p = threadIdx.x; p < 1280; p += 256) {
    const int d = p & 63;
    const int hh = p >> 6;
    const int col = (hh < 16) ? (hh * 128 + d) : (2048 + (hh - 16) * 128 + d);
    const float inv = exp2f((float)d * (-13.287712379549449f / 64.f));
    const float ang = (float)t * inv;
    float sn, cs;
    __sincosf(ang, &sn, &cs);
    __bf16* ptr = qkv + (size_t)row * 3072 + col;
    const float x1 = (float)ptr[0];
    const float x2 = (float)ptr[64];
    ptr[0] = (__bf16)(x1 * cs - x2 * sn);
    ptr[64] = (__bf16)(x2 * cs + x1 * sn);
  }
}

// ---------------------------------------------------------------- flash attention v3
// grid: (T/64, B*H), q-blocks REVERSED (longest first). 4 waves/block.
// Per 32-key tile: cooperative b128 staging of K-tile [32][136] and
// V^T-tile [128][40] in LDS; QK^T and PV fragments from LDS; 2 barriers.
constexpr int KS_LD = 136;  // 128 + 8 pad
constexpr int VS_LD = 40;   // 32 + 8 pad
__global__ __launch_bounds__(256) void flash_attn(const __bf16* __restrict__ qkv,
                                                  const __bf16* __restrict__ vtg,
                                                  __bf16* __restrict__ y) {
  const int b = blockIdx.y >> 4, h = blockIdx.y & 15;
  const int g = h >> 2;
  const int q0 = ((int)gridDim.x - 1 - (int)blockIdx.x) * 64;  // longest blocks first
  const int tid = threadIdx.x;
  const int wave = tid >> 6, lane = tid & 63;
  const int lr = lane & 15, lq = lane >> 4;

  const __bf16* Qb = qkv + (size_t)b * Tn * 3072 + h * 128;
  const __bf16* Kb = qkv + (size_t)b * Tn * 3072 + 2048 + g * 128;
  const __bf16* Vt = vtg + (size_t)(b * 4 + g) * 128 * Tn;  // [dim][key]

  __shared__ __attribute__((aligned(16))) __bf16 Ks[32 * KS_LD];
  __shared__ __attribute__((aligned(16))) __bf16 Vs[128 * VS_LD];
  __shared__ __attribute__((aligned(16))) __bf16 Pl[4][16 * 40];

  // staging maps (all b128):
  //   K: thread -> key krow=tid>>3, chunks kc0=(tid&7)*2, +1  (dims kc*8..+8)
  //   V: thread -> dim vrow=tid>>1, chunks vc0=(tid&1)*2, +1  (keys vc*8..+8)
  const int krow = tid >> 3, kc0 = (tid & 7) * 2;
  const int vrow = tid >> 1, vc0 = (tid & 1) * 2;

  // Q tile, A-operand layout
  const int qrow = q0 + wave * 16 + lr;
  bf16x8 qf[4];
#pragma unroll
  for (int f = 0; f < 4; ++f)
    qf[f] = *(const bf16x8*)(Qb + (size_t)qrow * 3072 + f * 32 + lq * 8);

  f32x4 o[8] = {};
  float m_i[4], l_i[4];
#pragma unroll
  for (int r = 0; r < 4; ++r) { m_i[r] = -1e30f; l_i[r] = 0.f; }
  const float scale = 0.08838834764831845f;  // 1/sqrt(128)

  for (int kt = 0; kt < q0 + 64; kt += 32) {
    __syncthreads();  // prev-iter LDS reads done
    {  // stage K-tile and V^T-tile (b128 only)
      const __bf16* kp = Kb + (size_t)(kt + krow) * 3072;
      *(bf16x8*)(Ks + krow * KS_LD + kc0 * 8)       = *(const bf16x8*)(kp + kc0 * 8);
      *(bf16x8*)(Ks + krow * KS_LD + (kc0 + 1) * 8) = *(const bf16x8*)(kp + (kc0 + 1) * 8);
      const __bf16* vp = Vt + (size_t)vrow * Tn + kt;
      *(bf16x8*)(Vs + vrow * VS_LD + vc0 * 8)       = *(const bf16x8*)(vp + vc0 * 8);
      *(bf16x8*)(Vs + vrow * VS_LD + (vc0 + 1) * 8) = *(const bf16x8*)(vp + (vc0 + 1) * 8);
    }
    __syncthreads();  // tiles visible

    // S = Q K^T : two 16-key tiles from LDS
    f32x4 s0 = {}, s1 = {};
#pragma unroll
    for (int f = 0; f < 4; ++f) {
      bf16x8 kf = *(const bf16x8*)(Ks + lr * KS_LD + f * 32 + lq * 8);
      s0 = mfma_bf16(qf[f], kf, s0);
    }
#pragma unroll
    for (int f = 0; f < 4; ++f) {
      bf16x8 kf = *(const bf16x8*)(Ks + (16 + lr) * KS_LD + f * 32 + lq * 8);
      s1 = mfma_bf16(qf[f], kf, s1);
    }

    // V^T B-fragments from LDS (dim n*16+lr, keys lq*8..+8)
    bf16x8 vv[8];
#pragma unroll
    for (int n = 0; n < 8; ++n)
      vv[n] = *(const bf16x8*)(Vs + (n * 16 + lr) * VS_LD + lq * 8);

    // online softmax (row lq*4+r, key cols lr / lr+16)
#pragma unroll
    for (int r = 0; r < 4; ++r) {
      const int q = q0 + wave * 16 + lq * 4 + r;
      const bool v0ok = (kt + lr) <= q;
      const bool v1ok = (kt + 16 + lr) <= q;
      float a0 = v0ok ? s0[r] * scale : -1e30f;
      float a1 = v1ok ? s1[r] * scale : -1e30f;
      float mx = fmaxf(a0, a1);
      mx = fmaxf(mx, __shfl_xor(mx, 1));
      mx = fmaxf(mx, __shfl_xor(mx, 2));
      mx = fmaxf(mx, __shfl_xor(mx, 4));
      mx = fmaxf(mx, __shfl_xor(mx, 8));
      const float mnew = fmaxf(m_i[r], mx);
      const float p0 = v0ok ? __expf(a0 - mnew) : 0.f;
      const float p1 = v1ok ? __expf(a1 - mnew) : 0.f;
      float rs = p0 + p1;
      rs += __shfl_xor(rs, 1);
      rs += __shfl_xor(rs, 2);
      rs += __shfl_xor(rs, 4);
      rs += __shfl_xor(rs, 8);
      const float alpha = __expf(m_i[r] - mnew);
      m_i[r] = mnew;
      l_i[r] = l_i[r] * alpha + rs;
#pragma unroll
      for (int n = 0; n < 8; ++n) o[n][r] *= alpha;
      Pl[wave][(lq * 4 + r) * 40 + lr] = (__bf16)p0;
      Pl[wave][(lq * 4 + r) * 40 + 16 + lr] = (__bf16)p1;
    }

    __threadfence_block();  // Pl is wave-private; order write->read

    bf16x8 pa = *(const bf16x8*)(&Pl[wave][lr * 40 + lq * 8]);
#pragma unroll
    for (int n = 0; n < 8; ++n)
      o[n] = mfma_bf16(pa, vv[n], o[n]);
  }

#pragma unroll
  for (int r = 0; r < 4; ++r) {
    const int q = q0 + wave * 16 + lq * 4 + r;
    const float inv = 1.0f / l_i[r];
#pragma unroll
    for (int n = 0; n < 8; ++n)
      y[(size_t)(b * Tn + q) * 2048 + h * 128 + n * 16 + lr] = (__bf16)(o[n][r] * inv);
  }
}

// ---------------------------------------------------------------- launch
extern "C" void kernel_launch(void* const* d_in, const int* in_sizes, int n_in,
                              void* d_out, int out_size, void* d_ws, size_t ws_size,
                              hipStream_t stream) {
  (void)in_sizes; (void)n_in; (void)out_size; (void)ws_size;
  const float* x  = (const float*)d_in[0];
  const float* Wq = (const float*)d_in[1];
  const float* Wk = (const float*)d_in[2];
  const float* Wv = (const float*)d_in[3];
  const float* Wo = (const float*)d_in[4];
  float* out = (float*)d_out;

  __bf16* xb  = (__bf16*)d_ws;                  // [4096][2048]; y aliases after gemm1
  __bf16* y   = xb;
  __bf16* WT  = xb + (size_t)4096 * 2048;       // [3072][2048]
  __bf16* WoT = WT;                             // [2048][2048] aliases after gemm1
  __bf16* VtG = WT + (size_t)2048 * 2048;       // [8][128][2048]
  __bf16* qkv = WT + (size_t)3072 * 2048;       // [4096][3072]

  convert_f32_bf16<<<(4096 * 2048 / 4 + 255) / 256, 256, 0, stream>>>(x, xb, 4096 * 2048 / 4);
  dim3 tb(32, 8);
  transpose_f32_bf16<<<dim3(64, 64), tb, 0, stream>>>(Wq, WT, 2048, 2048);
  transpose_f32_bf16<<<dim3(16, 64), tb, 0, stream>>>(Wk, WT + (size_t)2048 * 2048, 2048, 512);
  transpose_f32_bf16<<<dim3(16, 64), tb, 0, stream>>>(Wv, WT + (size_t)2560 * 2048, 2048, 512);

  gemm_bt<<<dim3(3072 / 128, 4096 / 128), 256, 0, stream>>>(xb, WT, qkv, 2048, 3072, 0);
  rope_kernel<<<4096, 256, 0, stream>>>(qkv);

  transpose_v<<<dim3(Tn / 32, 4, 8), tb, 0, stream>>>(qkv, VtG);
  transpose_f32_bf16<<<dim3(64, 64), tb, 0, stream>>>(Wo, WoT, 2048, 2048);

  flash_attn<<<dim3(Tn / 64, 2 * 16), 256, 0, stream>>>(qkv, VtG, y);
  gemm_bt<<<dim3(2048 / 128, 4096 / 128), 256, 0, stream>>>(y, WoT, out, 2048, 2048, 1);
}